// Round 1
// baseline (310.845 us; speedup 1.0000x reference)
//
#include <hip/hip_runtime.h>

// BSQ forward: x (65536x512 f32) -> z (x16) -> sign bits -> decode (x512).
// Normalize is sign-invariant -> skipped; STE forward output == sign(z).
//
// NUMERICS: borderline z (~1e-7) exist; must match the np reference's f32
// sign decisions BITWISE (numpy baseline SSE: separate mul+add, reversed
// subvector chain, 4 partials, SSE3 hadd tree, then +b_enc). We emulate
// with unfused mul/add chains; `#pragma clang fp contract(off)` blocks FMA
// contraction. v2f packing is numerics-identical per element (pk ops are
// two independent IEEE f32 ops).
//
// vs previous version: x is no longer staged through LDS. The 16-lane
// broadcast that the x-slab provided comes straight from the coalescer/L1
// (4 unique float4 per wave-op). This removes the 32-way-conflict
// ds_writes + per-round lgkmcnt(0) drains (measured 4.99M conflict cycles)
// and halves LDS (64->32 KB) -> 4 blocks/CU instead of 2.

typedef float v2f __attribute__((ext_vector_type(2)));

constexpr int DIM  = 512;
constexpr int NC   = 16;
constexpr int TPB  = 64;     // tokens per block
constexpr int NTOK = 65536;

__device__ __forceinline__ float add_rn(float a, float b) { return __fadd_rn(a, b); }
__device__ __forceinline__ v2f mk2(float a, float b) { v2f r; r.x = a; r.y = b; return r; }

__global__ __launch_bounds__(256, 4) void bsq_main(
    const float* __restrict__ x,
    const float* __restrict__ Wenc,   // (16, 512)
    const float* __restrict__ benc,   // (16,)
    const float* __restrict__ Wdec,   // (512, 16)
    const float* __restrict__ bdec,   // (512,)
    float* __restrict__ out)          // (65536, 512)
{
    // W layout: [col4 0..127][c 0..15] float4. Encode read: 16 unique
    // consecutive 16B addrs x 4-way broadcast -> 2-way bank alias = free.
    __shared__ float4 s_w4[2048];     // 32 KB (first 256 B reused for codes)

    const int tid  = threadIdx.x;
    const int lane = tid & 63;
    const int wv   = tid >> 6;        // wave 0..3, owns 16 tokens
    const int tsub = lane >> 4;       // token-in-round 0..3
    const int c    = lane & 15;       // channel
    const size_t tok0 = (size_t)blockIdx.x * TPB;

    // ---- stage W into LDS ----
    // Conflict-free: lane writes CONSECUTIVE LDS float4s (a = q*256+tid),
    // taking the permuted global index. (Old pattern was a 64-way write
    // conflict: 256 B lane stride -> single bank-quad.) W comes from L2
    // after the first block; scatter on the read side is non-critical.
    {
        const float4* wg = (const float4*)Wenc;
#pragma unroll
        for (int q = 0; q < 8; ++q) {
            int a = q * 256 + tid;                 // 0..2047, LDS index
            s_w4[a] = wg[(a & 15) * 128 + (a >> 4)]; // row c=a&15, col4=a>>4
        }
    }
    __syncthreads();

    const float bc = benc[c];
    unsigned mycode = 0;   // lanes 0..15 end up holding token (wv*16+lane)'s code

#pragma unroll 1
    for (int r = 0; r < 4; ++r) {
#pragma clang fp contract(off)
        // each lane reads its token's row directly from global:
        // per load op: 4 unique 16B addrs (one per tsub), 16-lane broadcast.
        // Offsets fold into the 13-bit imm; byte is fetched from HBM once.
        const float4* xr =
            (const float4*)(x + (tok0 + (size_t)(wv * 16 + r * 4 + tsub)) * DIM);

        v2f p01 = mk2(0.f, 0.f);      // numpy partials k%4 = {0,1}
        v2f p23 = mk2(0.f, 0.f);      // k%4 = {2,3}
#pragma unroll 4
        for (int i = 0; i < 32; ++i) {               // 16-element chunks
            float4 x0 = xr[4 * i + 0];
            float4 x1 = xr[4 * i + 1];
            float4 x2 = xr[4 * i + 2];
            float4 x3 = xr[4 * i + 3];
            float4 w0 = s_w4[(4 * i + 0) * 16 + c];
            float4 w1 = s_w4[(4 * i + 1) * 16 + c];
            float4 w2 = s_w4[(4 * i + 2) * 16 + c];
            float4 w3 = s_w4[(4 * i + 3) * 16 + c];
            // reversed subvector chain (a3 hits accumulator first), unfused.
            v2f t01, t23;
            t01 = mk2(x3.x, x3.y) * mk2(w3.x, w3.y) + p01;
            t01 = mk2(x2.x, x2.y) * mk2(w2.x, w2.y) + t01;
            t01 = mk2(x1.x, x1.y) * mk2(w1.x, w1.y) + t01;
            p01 = mk2(x0.x, x0.y) * mk2(w0.x, w0.y) + t01;
            t23 = mk2(x3.z, x3.w) * mk2(w3.z, w3.w) + p23;
            t23 = mk2(x2.z, x2.w) * mk2(w2.z, w2.w) + t23;
            t23 = mk2(x1.z, x1.w) * mk2(w1.z, w1.w) + t23;
            p23 = mk2(x0.z, x0.w) * mk2(w0.z, w0.w) + t23;
        }
        // SSE3 hadd tree, then + b_enc as separate add
        float zs = add_rn(add_rn(p01.x, p01.y), add_rn(p23.x, p23.y));
        float z  = add_rn(zs, bc);

        unsigned long long m = __ballot(z >= 0.0f);  // bit (16*tsub + c)
        if ((lane >> 2) == r)                        // lane 4r+u keeps token r*4+u
            mycode = (unsigned)((m >> ((lane & 3) * 16)) & 0xFFFFull);
    }

    // park codes in the now-dead head of the W slab (all W reads done)
    __syncthreads();
    if (lane < 16) ((unsigned*)s_w4)[wv * 16 + lane] = mycode;
    __syncthreads();

    // ---- decode: thread owns output columns 2*tid, 2*tid+1 ----
    v2f w01[NC];
    {
        const float4* wrow = (const float4*)(Wdec + tid * 32);
        float4 ra[4], rb[4];
#pragma unroll
        for (int p = 0; p < 4; ++p) ra[p] = wrow[p];
#pragma unroll
        for (int p = 0; p < 4; ++p) rb[p] = wrow[4 + p];
#pragma unroll
        for (int p = 0; p < 4; ++p) {
            w01[p * 4 + 0] = mk2(ra[p].x, rb[p].x);
            w01[p * 4 + 1] = mk2(ra[p].y, rb[p].y);
            w01[p * 4 + 2] = mk2(ra[p].z, rb[p].z);
            w01[p * 4 + 3] = mk2(ra[p].w, rb[p].w);
        }
    }
    const float2 bdv = *(const float2*)(bdec + 2 * tid);
    const v2f ob = mk2(bdv.x, bdv.y);
    float* op = out + tok0 * DIM + 2 * tid;

    // lane l holds code of block-token l
    int cv = (int)((const unsigned*)s_w4)[lane];
#pragma unroll 4
    for (int t2 = 0; t2 < TPB; ++t2) {
        unsigned code = (unsigned)__builtin_amdgcn_readlane(cv, t2); // wave-uniform
        v2f o = ob;
#pragma unroll
        for (int cc = 0; cc < NC; ++cc) {
            float s = ((code >> cc) & 1u) ? 1.0f : -1.0f;  // uniform -> SALU select
            o = __builtin_elementwise_fma(w01[cc], mk2(s, s), o);
        }
        *(float2*)(op + (size_t)t2 * DIM) = make_float2(o.x, o.y);   // coalesced
    }
}

extern "C" void kernel_launch(void* const* d_in, const int* in_sizes, int n_in,
                              void* d_out, int out_size, void* d_ws, size_t ws_size,
                              hipStream_t stream) {
    const float* x    = (const float*)d_in[0];
    const float* Wenc = (const float*)d_in[1];
    const float* benc = (const float*)d_in[2];
    const float* Wdec = (const float*)d_in[3];
    const float* bdec = (const float*)d_in[4];
    float* out = (float*)d_out;

    bsq_main<<<dim3(NTOK / TPB), dim3(256), 0, stream>>>(x, Wenc, benc, Wdec, bdec, out);
}

// Round 2
// 273.099 us; speedup vs baseline: 1.1382x; 1.1382x over previous
//
#include <hip/hip_runtime.h>

// BSQ forward: x (65536x512 f32) -> z (x16) -> sign bits -> decode (x512).
// Normalize is sign-invariant -> skipped; STE forward output == sign(z).
//
// NUMERICS: borderline z (~1e-7) exist; must match the np reference's f32
// sign decisions BITWISE (numpy baseline SSE: separate mul+add, reversed
// subvector chain, 4 partials p[k%4], SSE3 hadd tree, then +b_enc as a
// separate add). Unfused chains; `#pragma clang fp contract(off)` blocks
// FMA contraction. v2f packing is per-element-identical IEEE f32.
//
// vs 113us version: identical structure (LDS x-staging, 1-round register
// prefetch) but ALL LDS traffic is now bank-conflict-free:
//  - x slab XOR-swizzled: phys = col4*4 + (trow ^ ((col4>>1)&3)).
//    writes: 64 lanes spread over all 8 bank-quads (was 32-way conflict);
//    reads: 4 unique consecutive slots, 16-lane broadcast (still free).
//    XOR folds into 4 precomputed base pointers per side -> zero per-iter
//    address VALU; offsets become ds_read/write immediates.
//  - W stage writes linear (lane-consecutive), permuted global source
//    (was 64-way write conflict; W comes from L2, scatter there is free).
// Measured pathology this removes: SQ_LDS_BANK_CONFLICT = 4,988,928/dispatch.

typedef float v2f __attribute__((ext_vector_type(2)));

constexpr int DIM  = 512;
constexpr int NC   = 16;
constexpr int TPB  = 64;     // tokens per block
constexpr int NTOK = 65536;

__device__ __forceinline__ float add_rn(float a, float b) { return __fadd_rn(a, b); }
__device__ __forceinline__ v2f mk2(float a, float b) { v2f r; r.x = a; r.y = b; return r; }

__global__ __launch_bounds__(256, 2) void bsq_main(
    const float* __restrict__ x,
    const float* __restrict__ Wenc,   // (16, 512)
    const float* __restrict__ benc,   // (16,)
    const float* __restrict__ Wdec,   // (512, 16)
    const float* __restrict__ bdec,   // (512,)
    float* __restrict__ out)          // (65536, 512)
{
    // W: [col4 0..127][c 0..15] float4. Encode read op: 16 unique
    // consecutive 16B addrs x 4-way broadcast = data-minimum, free.
    __shared__ float4 s_w4[2048];        // 32 KB (head reused for codes)
    __shared__ float4 s_x4[4][512];      // 32 KB, wave-private swizzled slabs

    const int tid  = threadIdx.x;
    const int lane = tid & 63;
    const int wv   = tid >> 6;           // wave 0..3, owns 16 tokens
    const int tsub = lane >> 4;          // token-in-round 0..3
    const int c    = lane & 15;          // channel
    const size_t tok0 = (size_t)blockIdx.x * TPB;

    // ---- stage W into LDS (conflict-free: lane writes consecutive LDS
    // float4s, taking the permuted global index) ----
    {
        const float4* wg = (const float4*)Wenc;
#pragma unroll
        for (int q = 0; q < 8; ++q) {
            int a = q * 256 + tid;                   // 0..2047 LDS index
            s_w4[a] = wg[(a & 15) * 128 + (a >> 4)]; // row c=a&15, col4=a>>4
        }
    }
    __syncthreads();

    const float bc = benc[c];
    const float4* xg = (const float4*)(x + (tok0 + (size_t)wv * 16) * DIM);

    // swizzled x-slab base pointers.
    // write q: col4=(q&1)*64+lane, trow=q>>1 -> phys = lane*4 + (q&1)*256
    //          + ((q>>1)^kw), kw=(lane>>1)&3  (lane-constant)
    const int kw = (lane >> 1) & 3;
    float4* wp[4];
#pragma unroll
    for (int m = 0; m < 4; ++m) wp[m] = &s_x4[wv][lane * 4 + (m ^ kw)];
    // read (trow=tsub, col4): phys = col4*4 + (tsub ^ ((col4>>1)&3))
    const float4* rp[4];
#pragma unroll
    for (int k = 0; k < 4; ++k) rp[k] = &s_x4[wv][tsub ^ k];

    // prefetch round 0 (coalesced: consecutive lanes -> consecutive float4)
    float4 pf[8];
#pragma unroll
    for (int q = 0; q < 8; ++q) pf[q] = xg[q * 64 + lane];

    unsigned mycode = 0;   // lanes 0..15 end up holding token (wv*16+lane)'s code

#pragma unroll 1
    for (int r = 0; r < 4; ++r) {
#pragma clang fp contract(off)
        // write prefetched 4 tokens into this wave's swizzled slab
#pragma unroll
        for (int q = 0; q < 8; ++q)
            wp[q >> 1][(q & 1) * 256] = pf[q];
        // issue next round's global loads now; consumed next iteration
        if (r < 3) {
            const float4* nx = xg + (r + 1) * 512;
#pragma unroll
            for (int q = 0; q < 8; ++q) pf[q] = nx[q * 64 + lane];
        }
        // cross-lane LDS visibility within the wave (wave-private slab,
        // wave-lockstep, in-order DS pipe + explicit drain)
        asm volatile("s_waitcnt lgkmcnt(0)" ::: "memory");
        __builtin_amdgcn_wave_barrier();

        // ---- numpy SSE sum-of-products emulation ----
        v2f p01 = mk2(0.f, 0.f);      // numpy partials k%4 = {0,1}
        v2f p23 = mk2(0.f, 0.f);      // k%4 = {2,3}
#pragma unroll 4
        for (int i = 0; i < 32; ++i) {               // 16-element chunks
            // swizzle k for col4=4i+j: j=0,1 -> (2i)&3 ; j=2,3 -> (2i+1)&3
            const int k01 = (2 * i) & 3;
            const int k23 = (2 * i + 1) & 3;
            float4 x0 = rp[k01][(4 * i + 0) * 4];
            float4 x1 = rp[k01][(4 * i + 1) * 4];
            float4 x2 = rp[k23][(4 * i + 2) * 4];
            float4 x3 = rp[k23][(4 * i + 3) * 4];
            float4 w0 = s_w4[(4 * i + 0) * 16 + c];
            float4 w1 = s_w4[(4 * i + 1) * 16 + c];
            float4 w2 = s_w4[(4 * i + 2) * 16 + c];
            float4 w3 = s_w4[(4 * i + 3) * 16 + c];
            // reversed subvector chain (a3 hits accumulator first), unfused.
            v2f t01, t23;
            t01 = mk2(x3.x, x3.y) * mk2(w3.x, w3.y) + p01;
            t01 = mk2(x2.x, x2.y) * mk2(w2.x, w2.y) + t01;
            t01 = mk2(x1.x, x1.y) * mk2(w1.x, w1.y) + t01;
            p01 = mk2(x0.x, x0.y) * mk2(w0.x, w0.y) + t01;
            t23 = mk2(x3.z, x3.w) * mk2(w3.z, w3.w) + p23;
            t23 = mk2(x2.z, x2.w) * mk2(w2.z, w2.w) + t23;
            t23 = mk2(x1.z, x1.w) * mk2(w1.z, w1.w) + t23;
            p23 = mk2(x0.z, x0.w) * mk2(w0.z, w0.w) + t23;
        }
        // SSE3 hadd tree, then + b_enc as separate add
        float zs = add_rn(add_rn(p01.x, p01.y), add_rn(p23.x, p23.y));
        float z  = add_rn(zs, bc);

        unsigned long long m = __ballot(z >= 0.0f);  // bit (16*tsub + c)
        if ((lane >> 2) == r)                        // lane 4r+u keeps token r*4+u
            mycode = (unsigned)((m >> ((lane & 3) * 16)) & 0xFFFFull);
    }

    // park codes in the now-dead head of the W slab (all W reads done)
    __syncthreads();
    if (lane < 16) ((unsigned*)s_w4)[wv * 16 + lane] = mycode;
    __syncthreads();

    // ---- decode: thread owns output columns 2*tid, 2*tid+1 ----
    v2f w01[NC];
    {
        const float4* wrow = (const float4*)(Wdec + tid * 32);
        float4 ra[4], rb[4];
#pragma unroll
        for (int p = 0; p < 4; ++p) ra[p] = wrow[p];
#pragma unroll
        for (int p = 0; p < 4; ++p) rb[p] = wrow[4 + p];
#pragma unroll
        for (int p = 0; p < 4; ++p) {
            w01[p * 4 + 0] = mk2(ra[p].x, rb[p].x);
            w01[p * 4 + 1] = mk2(ra[p].y, rb[p].y);
            w01[p * 4 + 2] = mk2(ra[p].z, rb[p].z);
            w01[p * 4 + 3] = mk2(ra[p].w, rb[p].w);
        }
    }
    const float2 bdv = *(const float2*)(bdec + 2 * tid);
    const v2f ob = mk2(bdv.x, bdv.y);
    float* op = out + tok0 * DIM + 2 * tid;

    // lane l holds code of block-token l
    int cv = (int)((const unsigned*)s_w4)[lane];
#pragma unroll 4
    for (int t2 = 0; t2 < TPB; ++t2) {
        unsigned code = (unsigned)__builtin_amdgcn_readlane(cv, t2); // wave-uniform
        v2f o = ob;
#pragma unroll
        for (int cc = 0; cc < NC; ++cc) {
            float s = ((code >> cc) & 1u) ? 1.0f : -1.0f;  // uniform select
            o = __builtin_elementwise_fma(w01[cc], mk2(s, s), o);
        }
        *(float2*)(op + (size_t)t2 * DIM) = make_float2(o.x, o.y);   // coalesced
    }
}

extern "C" void kernel_launch(void* const* d_in, const int* in_sizes, int n_in,
                              void* d_out, int out_size, void* d_ws, size_t ws_size,
                              hipStream_t stream) {
    const float* x    = (const float*)d_in[0];
    const float* Wenc = (const float*)d_in[1];
    const float* benc = (const float*)d_in[2];
    const float* Wdec = (const float*)d_in[3];
    const float* bdec = (const float*)d_in[4];
    float* out = (float*)d_out;

    bsq_main<<<dim3(NTOK / TPB), dim3(256), 0, stream>>>(x, Wenc, benc, Wdec, bdec, out);
}